// Round 13
// baseline (182.804 us; speedup 1.0000x reference)
//
#include <hip/hip_runtime.h>
#include <cstdint>
#include <cstddef>

// EcoAttention: block-local top-p truncated attention, S=4096 D=128 BLOCK=64.
//
// R13: concurrency round (R12 proved per-wave-latency-bound, not VALU-bound).
//  - Bitonic sort RESTORED (R12's max-extraction: fewer VALU ops but a serial
//    dependence chain -> slower. High-ILP issue-heavy wins when slots idle).
//  - Kr residual plane read DIRECT from L2 in frag-linear order (like Vt);
//    only the Khi plane is LDS-staged (dedup kept -> no R11 traffic blowup).
//    LDS 40KB -> 24KB => 6 WG/CU = 24 waves/CU.
//  - Grid 64 ib x 24 jg = 1536 WGs = exactly 6/CU (no batch tail); jg<16
//    handles 3 j-blocks, jg>=16 handles 2 (16*3 + 8*2 = 64).

#define SEQ   4096
#define DIM   128
#define BLK   64
#define NB    (SEQ / BLK)   // 64
#define NJG   24            // j-groups (1536 WGs total)
#define NT    256
#define PSTR  12288         // uints per prepped block (Khi-img 16KB | Kr-frag 16KB | Vt-frag 16KB)
#define THRESH 0.95f
#define EPSF   1e-8f

typedef __attribute__((ext_vector_type(8))) _Float16 f16x8;
typedef __attribute__((ext_vector_type(4))) float    f32x4;

#define MFMAH(a, b, c) __builtin_amdgcn_mfma_f32_16x16x32_f16((a), (b), (c), 0, 0, 0)

union UH4 { uint2 u; _Float16 h[4]; };
union UH8 { uint4 u; f16x8 v; };

__device__ __forceinline__ void gll16(const uint* g, uint* l) {
  __builtin_amdgcn_global_load_lds(
      (const __attribute__((address_space(1))) void*)g,
      (__attribute__((address_space(3))) void*)l, 16, 0, 0);
}

// ---- prep: LDS-free, 4 WGs per key block. Builds per-block 48KB image:
//      Khi swizzled LDS-image | Kr frag-linear | Vt frag-linear; zeroes O. ----
__global__ __launch_bounds__(NT, 4) void eco_prep_kernel(
    const float* __restrict__ K, const float* __restrict__ V,
    uint* __restrict__ P, float* __restrict__ O) {
  const int tid  = threadIdx.x;
  const int b    = blockIdx.x;     // 0..255
  const int jb   = b >> 2;
  const int part = b & 3;

  // zero O slice (2MB spread over 256 WGs)
  {
    float4 z = {0.f, 0.f, 0.f, 0.f};
    float4* op = (float4*)O;
#pragma unroll
    for (int it = 0; it < 2; ++it) op[b * 512 + it * NT + tid] = z;
  }

  // K 2-term f16 split: hi -> swizzled LDS-image order (staged via gll16 in
  // main), residual -> A-frag linear order (read direct from L2 in main).
  {
    const float4* gk = (const float4*)(K + (size_t)jb * BLK * DIM);
    uint* dh = P + (size_t)jb * PSTR;          // Khi image
    uint* dr = dh + 4096;                      // Kr frags
#pragma unroll
    for (int it = 0; it < 2; ++it) {
      int f = part * 512 + it * NT + tid;   // float4 idx 0..2047
      int r = f >> 5, c4 = f & 31;
      float4 x = gk[f];
      float xs[4] = {x.x, x.y, x.z, x.w};
      UH4 uh, ur;
#pragma unroll
      for (int e = 0; e < 4; ++e) {
        float v = xs[e];
        _Float16 h = (_Float16)v;
        uh.h[e] = h;
        ur.h[e] = (_Float16)(v - (float)h);   // exact residual (Sterbenz)
      }
      uint offh = (uint)r * 64u + (((uint)(c4 >> 1) ^ (uint)(r & 15)) << 2) +
                  (uint)((c4 & 1) << 1);
      // frag fi = (c/8)*64 + r = (c4>>1)*64 + r; uint-in-frag = (c4&1)*2
      uint offr = ((((uint)(c4 >> 1)) * 64u + (uint)r) << 2) +
                  (uint)((c4 & 1) << 1);
      *(uint2*)&dh[offh] = uh.u;
      *(uint2*)&dr[offr] = ur.u;
    }
  }

  // Vt in PV B-frag linear order: 1024 fragments; frag idx = ch*128 + d,
  // 8 f16 = V[ch*8+j][d]. One frag/thread.
  {
    const float* gv = V + (size_t)jb * BLK * DIM;
    uint4* dv = (uint4*)(P + (size_t)jb * PSTR + 8192);
    int idx = part * 256 + tid;            // frag idx 0..1023
    int ch = idx >> 7, d = idx & 127;
    UH8 u;
#pragma unroll
    for (int j = 0; j < 8; ++j)
      u.v[j] = (_Float16)gv[(ch * 8 + j) * DIM + d];
    dv[idx] = u.u;
  }
}

// lane-uniform-direction compare-exchange (desc if d)
#define CE(x, y, dmax) { float _hi = fmaxf((x), (y)); float _lo = fminf((x), (y)); \
                         (x) = (dmax) ? _hi : _lo; (y) = (dmax) ? _lo : _hi; }

__global__ __launch_bounds__(NT, 6) void eco_attn_kernel(
    const float* __restrict__ Q, const uint* __restrict__ P,
    float* __restrict__ O) {
  __shared__ __align__(16) uint sK[4096];   // 16 KB: Khi plane only
  __shared__ __align__(16) uint sW[2048];   // 8 KB: 4 x (16 rows x 32 uints)

  const int tid  = threadIdx.x;
  const int ib   = blockIdx.y;
  const int jg   = blockIdx.x;              // 0..23
  const int lane = tid & 63;
  const int wv   = tid >> 6;
  const int quad = lane >> 4;   // 0..3
  const int l16  = lane & 15;
  const int q4   = quad << 2;

  // uneven j-split: 16 WGs x 3 blocks + 8 WGs x 2 blocks = 64
  const int jb0 = (jg < 16) ? (3 * jg) : (48 + 2 * (jg - 16));
  const int nj  = (jg < 16) ? 3 : 2;

  uint* sWw = sW + wv * 512;    // this wave's weight rows (16 x 32 uints)

  // ---- Q fragments (B-operand): q-row = wv*16+l16, k = ks*32+quad*8+j ----
  f16x8 qh[4], qr[4];
  {
    const float* qp = Q + (size_t)(ib * BLK + wv * 16 + l16) * DIM + quad * 8;
#pragma unroll
    for (int ks = 0; ks < 4; ++ks) {
      float4 x0 = *(const float4*)(qp + ks * 32);
      float4 x1 = *(const float4*)(qp + ks * 32 + 4);
      float xs[8] = {x0.x, x0.y, x0.z, x0.w, x1.x, x1.y, x1.z, x1.w};
      f16x8 h8, r8;
#pragma unroll
      for (int e = 0; e < 8; ++e) {
        float v = xs[e];
        _Float16 h = (_Float16)v;
        h8[e] = h;
        r8[e] = (_Float16)(v - (float)h);
      }
      qh[ks] = h8; qr[ks] = r8;
    }
  }

  const f32x4 zf = {0.f, 0.f, 0.f, 0.f};
  f32x4 pv[8];
#pragma unroll
  for (int i = 0; i < 8; ++i) pv[i] = zf;

  // prologue: stage first Khi image (16KB = 4 x 16B per thread)
  {
    const uint* gsrc = P + (size_t)jb0 * PSTR;
#pragma unroll
    for (int it = 0; it < 4; ++it) {
      int idx = (it * NT + tid) << 2;
      gll16(gsrc + idx, sK + idx);
    }
  }

  for (int jj = 0; jj < nj; ++jj) {
    const int jb = jb0 + jj;
    const uint* kr  = P + (size_t)jb * PSTR + 4096;   // Kr frags (L2)
    const uint* gvt = P + (size_t)jb * PSTR + 8192;   // Vt frags (L2)
    __syncthreads();  // B1: Khi image staged (vmcnt drained by barrier)

    // ---- QK^T, operand-swapped: A = K (hi from LDS, res from L2),
    //      B = Q (resident). C: col(l16)=Q-row, row(quad*4+reg)=K-row ----
    f32x4 ah[4], ar[4];
#pragma unroll
    for (int nt = 0; nt < 4; ++nt) { ah[nt] = zf; ar[nt] = zf; }
#pragma unroll
    for (int nt = 0; nt < 4; ++nt) {
      const int rB = nt * 16 + l16;      // K-row for the A-frag read
      const uint rowoff = (uint)rB * 64u;
      const uint swk = (uint)(rB & 15);
#pragma unroll
      for (int ks = 0; ks < 4; ++ks) {
        uint off = rowoff + ((((uint)(ks * 4 + quad)) ^ swk) << 2);
        f16x8 bh = *(const f16x8*)&sK[off];
        f16x8 br = *(const f16x8*)&kr[((uint)((ks * 4 + quad) * 64 + rB)) << 2];
        ah[nt] = MFMAH(bh, qh[ks], ah[nt]);
        ar[nt] = MFMAH(br, qh[ks], ar[nt]);
        ar[nt] = MFMAH(bh, qr[ks], ar[nt]);
      }
    }
    __syncthreads();  // B0: all waves done reading sK

    // ---- prefetch next Khi image (overlaps sort + PV below) ----
    if (jj + 1 < nj) {
      const uint* gsrc = P + (size_t)(jb + 1) * PSTR;
#pragma unroll
      for (int it = 0; it < 4; ++it) {
        int idx = (it * NT + tid) << 2;
        gll16(gsrc + idx, sK + idx);
      }
    }

    // ---- top-p softmax, register-direct: lane owns Q-row wv*16+l16;
    //      a[i] (i = nt*4+rg) is score at K-index nt*16 + q4 + rg ----
    {
      float a[16], e[16];
#pragma unroll
      for (int nt = 0; nt < 4; ++nt) {
        f32x4 s = ah[nt] + ar[nt];
#pragma unroll
        for (int rg = 0; rg < 4; ++rg) a[nt * 4 + rg] = s[rg];
      }
      // row max: local tree + cross-quad
      float mt[8];
#pragma unroll
      for (int i = 0; i < 8; ++i) mt[i] = fmaxf(a[i], a[i + 8]);
#pragma unroll
      for (int w2 = 4; w2 >= 1; w2 >>= 1)
#pragma unroll
        for (int i = 0; i < w2; ++i) mt[i] = fmaxf(mt[i], mt[i + w2]);
      float m = mt[0];
      m = fmaxf(m, __shfl_xor(m, 16, 64));
      m = fmaxf(m, __shfl_xor(m, 32, 64));
#pragma unroll
      for (int i = 0; i < 16; ++i) { a[i] = __expf(a[i] - m); e[i] = a[i]; }
      float st[8];
#pragma unroll
      for (int i = 0; i < 8; ++i) st[i] = a[i] + a[i + 8];
#pragma unroll
      for (int w2 = 4; w2 >= 1; w2 >>= 1)
#pragma unroll
        for (int i = 0; i < w2; ++i) st[i] += st[i + w2];
      float sr = st[0];
      sr += __shfl_xor(sr, 16, 64);
      sr += __shfl_xor(sr, 32, 64);
      const float T = THRESH * sr;

      // bitonic sort DESC over 64 = 4 quad-lanes x 16 regs (value-sort)
      const int s = quad;
#pragma unroll
      for (int k2 = 2; k2 <= 8; k2 <<= 1)
#pragma unroll
        for (int j2 = k2 >> 1; j2 >= 1; j2 >>= 1)
#pragma unroll
          for (int i = 0; i < 16; ++i) {
            int l = i ^ j2;
            if (l > i) { bool d = ((i & k2) == 0); CE(a[i], a[l], d); }
          }
      const bool x16 = ((s & 1) == 0);
      const bool x32 = ((s & 2) == 0);
#pragma unroll
      for (int j2 = 8; j2 >= 1; j2 >>= 1)
#pragma unroll
        for (int i = 0; i < 16; ++i) {
          int l = i ^ j2;
          if (l > i) { CE(a[i], a[l], x16); }
        }
      {
        const bool km = (x32 == x16);
#pragma unroll
        for (int i = 0; i < 16; ++i) {
          float o = __shfl_xor(a[i], 16, 64);
          a[i] = km ? fmaxf(a[i], o) : fminf(a[i], o);
        }
#pragma unroll
        for (int j2 = 8; j2 >= 1; j2 >>= 1)
#pragma unroll
          for (int i = 0; i < 16; ++i) {
            int l = i ^ j2;
            if (l > i) { CE(a[i], a[l], x32); }
          }
      }
      {
#pragma unroll
        for (int i = 0; i < 16; ++i) {
          float o = __shfl_xor(a[i], 32, 64);
          a[i] = x32 ? fmaxf(a[i], o) : fminf(a[i], o);
        }
#pragma unroll
        for (int i = 0; i < 16; ++i) {
          float o = __shfl_xor(a[i], 16, 64);
          a[i] = x16 ? fmaxf(a[i], o) : fminf(a[i], o);
        }
#pragma unroll
        for (int j2 = 8; j2 >= 1; j2 >>= 1)
#pragma unroll
          for (int i = 0; i < 16; ++i) {
            int l = i ^ j2;
            if (l > i) { CE(a[i], a[l], true); }
          }
      }
      // global inclusive cumsum, count t
#pragma unroll
      for (int i = 1; i < 16; ++i) a[i] += a[i - 1];
      float tot = a[15];
      float c = tot;
      float o1 = __shfl_up(c, 16, 64); if (s >= 1) c += o1;
      float o2 = __shfl_up(c, 32, 64); if (s >= 2) c += o2;
      const float excl = c - tot;
      int cnt = 0;
#pragma unroll
      for (int i = 0; i < 16; ++i) cnt += ((a[i] + excl) < T) ? 1 : 0;
      cnt += __shfl_xor(cnt, 16, 64);
      cnt += __shfl_xor(cnt, 32, 64);
      const int t = cnt;
      // renormalize first-t (ORIGINAL K order; kidx = nt*16 + q4 + rg)
      float p = 0.f;
#pragma unroll
      for (int i = 0; i < 16; ++i) {
        int kidx = ((i >> 2) << 4) + q4 + (i & 3);
        p += (kidx < t) ? e[i] : 0.f;
      }
      p += __shfl_xor(p, 16, 64);
      p += __shfl_xor(p, 32, 64);
      const float rn = 1.0f / (p + EPSF);
      // emit f16 weights: row l16, 16 chunks of 4 f16; chunk c4 = nt*4+quad
      // at swizzled uint offset row*32 + ((c4 ^ row) << 1)
      uint* wrow = sWw + l16 * 32;
#pragma unroll
      for (int nt = 0; nt < 4; ++nt) {
        UH4 u;
#pragma unroll
        for (int rg = 0; rg < 4; ++rg) {
          int kidx = nt * 16 + q4 + rg;
          float wgt = (kidx < t) ? e[nt * 4 + rg] * rn : 0.f;
          u.h[rg] = (_Float16)wgt;
        }
        uint c4 = (uint)(nt * 4 + quad);
        *(uint2*)&wrow[(c4 ^ (uint)l16) << 1] = u.u;
      }
    }
    __builtin_amdgcn_wave_barrier();  // weight writes before A-frag reads

    // ---- PV: A = f16 weights (wave-private LDS), B = Vt-frag from global ----
    f16x8 wf[2];
#pragma unroll
    for (int ks2 = 0; ks2 < 2; ++ks2) {
      uint c0 = (uint)(ks2 * 8 + quad * 2);
      const uint* wrow = sWw + l16 * 32;
      uint2 lo = *(const uint2*)&wrow[(c0 ^ (uint)l16) << 1];
      uint2 hi = *(const uint2*)&wrow[((c0 + 1) ^ (uint)l16) << 1];
      UH8 u;
      u.u = make_uint4(lo.x, lo.y, hi.x, hi.y);
      wf[ks2] = u.v;
    }
#pragma unroll
    for (int nt2 = 0; nt2 < 8; ++nt2) {
#pragma unroll
      for (int ks2 = 0; ks2 < 2; ++ks2) {
        f16x8 vf = *(const f16x8*)&gvt[((uint)((ks2 * 4 + quad) * 128 +
                                               nt2 * 16 + l16)) << 2];
        pv[nt2] = MFMAH(wf[ks2], vf, pv[nt2]);
      }
    }
    __builtin_amdgcn_wave_barrier();  // PV weight reads before next-iter writes
  }

  // ---- epilogue: C-layout -> global atomicAdd over the 24 j-groups ----
#pragma unroll
  for (int nt2 = 0; nt2 < 8; ++nt2) {
    const int col  = nt2 * 16 + l16;
    const int row0 = ib * BLK + wv * 16 + quad * 4;
#pragma unroll
    for (int rg = 0; rg < 4; ++rg)
      atomicAdd(O + (size_t)(row0 + rg) * DIM + col, pv[nt2][rg]);
  }
}

extern "C" void kernel_launch(void* const* d_in, const int* in_sizes, int n_in,
                              void* d_out, int out_size, void* d_ws, size_t ws_size,
                              hipStream_t stream) {
  (void)in_sizes; (void)n_in; (void)ws_size; (void)out_size;
  const float* q = (const float*)d_in[0];
  const float* k = (const float*)d_in[1];
  const float* v = (const float*)d_in[2];
  float* out = (float*)d_out;
  uint* prep = (uint*)d_ws;   // 64 blocks x 48 KB = 3 MB

  eco_prep_kernel<<<dim3(NB * 4), dim3(NT), 0, stream>>>(k, v, prep, out);
  eco_attn_kernel<<<dim3(NJG, NB), dim3(NT), 0, stream>>>(q, prep, out);
}

// Round 14
// 157.014 us; speedup vs baseline: 1.1643x; 1.1643x over previous
//
#include <hip/hip_runtime.h>
#include <cstdint>
#include <cstddef>

// EcoAttention: block-local top-p truncated attention, S=4096 D=128 BLOCK=64.
//
// R14 = R10 staging (Khi+Kr LDS-staged 32KB — R11/R13 proved direct per-wave
//       K reads blow L2/HBM; Vt direct is fine) + prep-side K-ROW PERMUTATION:
//       image pos p = nt*16+q*4+rg holds original K row
//       o(p) = (nt&1)*32 + q*8 + (nt>>1)*4 + rg  (bijection).
//       => each lane's 16 post-softmax weights ARE its PV A-fragment:
//       weight LDS round-trip, sW buffer, and wave-barriers deleted.
//       LDS 40KB -> 32KB => 5 WG/CU; NJG=20 (1280 WGs = exactly 5/CU).

#define SEQ   4096
#define DIM   128
#define BLK   64
#define NB    (SEQ / BLK)   // 64
#define NJG   20            // j-groups per ib (4x4jb + 16x3jb = 64)
#define NT    256
#define PSTR  12288         // uints per prepped block (Khi 16KB | Kr 16KB | Vt 16KB)
#define THRESH 0.95f
#define EPSF   1e-8f

typedef __attribute__((ext_vector_type(8))) _Float16 f16x8;
typedef __attribute__((ext_vector_type(4))) float    f32x4;

#define MFMAH(a, b, c) __builtin_amdgcn_mfma_f32_16x16x32_f16((a), (b), (c), 0, 0, 0)

union UH4 { uint2 u; _Float16 h[4]; };
union UH8 { uint4 u; f16x8 v; };

__device__ __forceinline__ void gll16(const uint* g, uint* l) {
  __builtin_amdgcn_global_load_lds(
      (const __attribute__((address_space(1))) void*)g,
      (__attribute__((address_space(3))) void*)l, 16, 0, 0);
}

// ---- prep: LDS-free, 4 WGs per key block. Builds [Khi|Kr|Vt-frag] 48KB
//      images (K rows PERMUTED by o(p)) in d_ws and zeroes O. ----
__global__ __launch_bounds__(NT, 4) void eco_prep_kernel(
    const float* __restrict__ K, const float* __restrict__ V,
    uint* __restrict__ P, float* __restrict__ O) {
  const int tid  = threadIdx.x;
  const int b    = blockIdx.x;     // 0..255
  const int jb   = b >> 2;
  const int part = b & 3;

  // zero O slice (2MB spread over 256 WGs)
  {
    float4 z = {0.f, 0.f, 0.f, 0.f};
    float4* op = (float4*)O;
#pragma unroll
    for (int it = 0; it < 2; ++it) op[b * 512 + it * NT + tid] = z;
  }

  // K 2-term f16 split -> swizzled planes, with row permutation:
  // image row r holds original K row o(r) = (nt&1)*32 + q*8 + (nt>>1)*4 + rg
  // where r = nt*16 + q*4 + rg.
  {
    const float4* gk = (const float4*)(K + (size_t)jb * BLK * DIM);
    uint* dst = P + (size_t)jb * PSTR;
#pragma unroll
    for (int it = 0; it < 2; ++it) {
      int f = part * 512 + it * NT + tid;   // image float4 idx 0..2047
      int r = f >> 5, c4 = f & 31;
      int nt = r >> 4, q = (r >> 2) & 3, rg = r & 3;
      int o  = (nt & 1) * 32 + q * 8 + ((nt >> 1) << 2) + rg;
      float4 x = gk[o * 32 + c4];
      float xs[4] = {x.x, x.y, x.z, x.w};
      UH4 uh, ur;
#pragma unroll
      for (int e = 0; e < 4; ++e) {
        float v = xs[e];
        _Float16 h = (_Float16)v;
        uh.h[e] = h;
        ur.h[e] = (_Float16)(v - (float)h);   // exact residual (Sterbenz)
      }
      uint off = (uint)r * 64u + (((uint)(c4 >> 1) ^ (uint)(r & 15)) << 2) +
                 (uint)((c4 & 1) << 1);
      *(uint2*)&dst[off]        = uh.u;
      *(uint2*)&dst[4096 + off] = ur.u;
    }
  }

  // Vt in PV B-frag linear order (ORIGINAL row order): 1024 fragments;
  // frag idx = ch*128 + d, 8 f16 = V[ch*8+j][d]. One frag/thread.
  {
    const float* gv = V + (size_t)jb * BLK * DIM;
    uint4* dv = (uint4*)(P + (size_t)jb * PSTR + 8192);
    int idx = part * 256 + tid;            // frag idx 0..1023
    int ch = idx >> 7, d = idx & 127;
    UH8 u;
#pragma unroll
    for (int j = 0; j < 8; ++j)
      u.v[j] = (_Float16)gv[(ch * 8 + j) * DIM + d];
    dv[idx] = u.u;
  }
}

// lane-uniform-direction compare-exchange (desc if d)
#define CE(x, y, dmax) { float _hi = fmaxf((x), (y)); float _lo = fminf((x), (y)); \
                         (x) = (dmax) ? _hi : _lo; (y) = (dmax) ? _lo : _hi; }

__global__ __launch_bounds__(NT, 5) void eco_attn_kernel(
    const float* __restrict__ Q, const uint* __restrict__ P,
    float* __restrict__ O) {
  __shared__ __align__(16) uint sK[8192];   // 32 KB: Khi / Kr planes

  const int tid  = threadIdx.x;
  const int ib   = blockIdx.y;
  const int jg   = blockIdx.x;              // 0..19
  const int lane = tid & 63;
  const int wv   = tid >> 6;
  const int quad = lane >> 4;   // 0..3
  const int l16  = lane & 15;
  const int q8   = quad << 3;

  // uneven j-split: 4 WGs x 4 blocks + 16 WGs x 3 blocks = 64
  const int jb0 = (jg < 4) ? (4 * jg) : (16 + 3 * (jg - 4));
  const int nj  = (jg < 4) ? 4 : 3;

  // ---- Q fragments (B-operand): q-row = wv*16+l16, k = ks*32+quad*8+j ----
  f16x8 qh[4], qr[4];
  {
    const float* qp = Q + (size_t)(ib * BLK + wv * 16 + l16) * DIM + quad * 8;
#pragma unroll
    for (int ks = 0; ks < 4; ++ks) {
      float4 x0 = *(const float4*)(qp + ks * 32);
      float4 x1 = *(const float4*)(qp + ks * 32 + 4);
      float xs[8] = {x0.x, x0.y, x0.z, x0.w, x1.x, x1.y, x1.z, x1.w};
      f16x8 h8, r8;
#pragma unroll
      for (int e = 0; e < 8; ++e) {
        float v = xs[e];
        _Float16 h = (_Float16)v;
        h8[e] = h;
        r8[e] = (_Float16)(v - (float)h);
      }
      qh[ks] = h8; qr[ks] = r8;
    }
  }

  const f32x4 zf = {0.f, 0.f, 0.f, 0.f};
  f32x4 pv[8];
#pragma unroll
  for (int i = 0; i < 8; ++i) pv[i] = zf;

  // prologue: stage first K image (32KB = 8 x 16B per thread)
  {
    const uint* gsrc = P + (size_t)jb0 * PSTR;
#pragma unroll
    for (int it = 0; it < 8; ++it) {
      int idx = (it * NT + tid) << 2;
      gll16(gsrc + idx, sK + idx);
    }
  }

  for (int jj = 0; jj < nj; ++jj) {
    const int jb = jb0 + jj;
    const uint* gvt = P + (size_t)jb * PSTR + 8192;   // Vt frags (L2)
    __syncthreads();  // B1: K image staged (vmcnt drained by barrier)

    // ---- QK^T, operand-swapped: A = K (LDS, permuted rows), B = Q ----
    // Lane (l16,quad) ends with scores at image rows nt*16+quad*4+rg,
    // i.e. original kidx = (nt&1)*32 + quad*8 + (nt>>1)*4 + rg.
    f32x4 ah[4], ar[4];
#pragma unroll
    for (int nt = 0; nt < 4; ++nt) { ah[nt] = zf; ar[nt] = zf; }
#pragma unroll
    for (int nt = 0; nt < 4; ++nt) {
      const int rB = nt * 16 + l16;      // image K-row for the A-frag read
      const uint rowoff = (uint)rB * 64u;
      const uint swk = (uint)(rB & 15);
#pragma unroll
      for (int ks = 0; ks < 4; ++ks) {
        uint off = rowoff + ((((uint)(ks * 4 + quad)) ^ swk) << 2);
        f16x8 bh = *(const f16x8*)&sK[off];
        f16x8 br = *(const f16x8*)&sK[4096 + off];
        ah[nt] = MFMAH(bh, qh[ks], ah[nt]);
        ar[nt] = MFMAH(br, qh[ks], ar[nt]);
        ar[nt] = MFMAH(bh, qr[ks], ar[nt]);
      }
    }
    __syncthreads();  // B0: all waves done reading sK

    // ---- prefetch next K image (overlaps sort + PV below) ----
    if (jj + 1 < nj) {
      const uint* gsrc = P + (size_t)(jb + 1) * PSTR;
#pragma unroll
      for (int it = 0; it < 8; ++it) {
        int idx = (it * NT + tid) << 2;
        gll16(gsrc + idx, sK + idx);
      }
    }

    // ---- top-p softmax + in-lane weight build; then PV ----
    f16x8 wf[2];
    {
      float a[16], e[16];
#pragma unroll
      for (int nt = 0; nt < 4; ++nt) {
        f32x4 s = ah[nt] + ar[nt];
#pragma unroll
        for (int rg = 0; rg < 4; ++rg) a[nt * 4 + rg] = s[rg];
      }
      // row max: local tree + cross-quad (lanes l16, +16, +32, +48)
      float mt[8];
#pragma unroll
      for (int i = 0; i < 8; ++i) mt[i] = fmaxf(a[i], a[i + 8]);
#pragma unroll
      for (int w2 = 4; w2 >= 1; w2 >>= 1)
#pragma unroll
        for (int i = 0; i < w2; ++i) mt[i] = fmaxf(mt[i], mt[i + w2]);
      float m = mt[0];
      m = fmaxf(m, __shfl_xor(m, 16, 64));
      m = fmaxf(m, __shfl_xor(m, 32, 64));
#pragma unroll
      for (int i = 0; i < 16; ++i) { a[i] = __expf(a[i] - m); e[i] = a[i]; }
      float st[8];
#pragma unroll
      for (int i = 0; i < 8; ++i) st[i] = a[i] + a[i + 8];
#pragma unroll
      for (int w2 = 4; w2 >= 1; w2 >>= 1)
#pragma unroll
        for (int i = 0; i < w2; ++i) st[i] += st[i + w2];
      float sr = st[0];
      sr += __shfl_xor(sr, 16, 64);
      sr += __shfl_xor(sr, 32, 64);
      const float T = THRESH * sr;

      // bitonic sort DESC over 64 = 4 quad-lanes x 16 regs (value-sort;
      // initial permutation irrelevant)
      const int s = quad;
#pragma unroll
      for (int k2 = 2; k2 <= 8; k2 <<= 1)
#pragma unroll
        for (int j2 = k2 >> 1; j2 >= 1; j2 >>= 1)
#pragma unroll
          for (int i = 0; i < 16; ++i) {
            int l = i ^ j2;
            if (l > i) { bool d = ((i & k2) == 0); CE(a[i], a[l], d); }
          }
      const bool x16 = ((s & 1) == 0);
      const bool x32 = ((s & 2) == 0);
#pragma unroll
      for (int j2 = 8; j2 >= 1; j2 >>= 1)
#pragma unroll
        for (int i = 0; i < 16; ++i) {
          int l = i ^ j2;
          if (l > i) { CE(a[i], a[l], x16); }
        }
      {
        const bool km = (x32 == x16);
#pragma unroll
        for (int i = 0; i < 16; ++i) {
          float o = __shfl_xor(a[i], 16, 64);
          a[i] = km ? fmaxf(a[i], o) : fminf(a[i], o);
        }
#pragma unroll
        for (int j2 = 8; j2 >= 1; j2 >>= 1)
#pragma unroll
          for (int i = 0; i < 16; ++i) {
            int l = i ^ j2;
            if (l > i) { CE(a[i], a[l], x32); }
          }
      }
      {
#pragma unroll
        for (int i = 0; i < 16; ++i) {
          float o = __shfl_xor(a[i], 32, 64);
          a[i] = x32 ? fmaxf(a[i], o) : fminf(a[i], o);
        }
#pragma unroll
        for (int i = 0; i < 16; ++i) {
          float o = __shfl_xor(a[i], 16, 64);
          a[i] = x16 ? fmaxf(a[i], o) : fminf(a[i], o);
        }
#pragma unroll
        for (int j2 = 8; j2 >= 1; j2 >>= 1)
#pragma unroll
          for (int i = 0; i < 16; ++i) {
            int l = i ^ j2;
            if (l > i) { CE(a[i], a[l], true); }
          }
      }
      // global inclusive cumsum, count t
#pragma unroll
      for (int i = 1; i < 16; ++i) a[i] += a[i - 1];
      float tot = a[15];
      float c = tot;
      float o1 = __shfl_up(c, 16, 64); if (s >= 1) c += o1;
      float o2 = __shfl_up(c, 32, 64); if (s >= 2) c += o2;
      const float excl = c - tot;
      int cnt = 0;
#pragma unroll
      for (int i = 0; i < 16; ++i) cnt += ((a[i] + excl) < T) ? 1 : 0;
      cnt += __shfl_xor(cnt, 16, 64);
      cnt += __shfl_xor(cnt, 32, 64);
      const int t = cnt;
      // renormalize first-t in ORIGINAL K order:
      // kidx(i) = (nt&1)*32 + quad*8 + (nt>>1)*4 + rg,  i = nt*4+rg
      float p = 0.f;
#pragma unroll
      for (int i = 0; i < 16; ++i) {
        int nt = i >> 2, rg = i & 3;
        int kidx = ((nt & 1) << 5) + q8 + ((nt >> 1) << 2) + rg;
        p += (kidx < t) ? e[i] : 0.f;
      }
      p += __shfl_xor(p, 16, 64);
      p += __shfl_xor(p, 32, 64);
      const float rn = 1.0f / (p + EPSF);
      // in-lane PV A-frag build: wf[ks2][jhi*4+rg] = w(kidx=ks2*32+q8+jhi*4+rg)
      // source element i = (2*jhi+ks2)*4 + rg
#pragma unroll
      for (int ks2 = 0; ks2 < 2; ++ks2) {
        UH8 u;
#pragma unroll
        for (int jhi = 0; jhi < 2; ++jhi)
#pragma unroll
          for (int rg = 0; rg < 4; ++rg) {
            int kidx = (ks2 << 5) + q8 + (jhi << 2) + rg;
            float w = (kidx < t) ? e[(2 * jhi + ks2) * 4 + rg] * rn : 0.f;
            u.v[jhi * 4 + rg] = (_Float16)w;
          }
        wf[ks2] = u.v;
      }
    }

    // ---- PV: A = in-register f16 weights, B = Vt-frag from global (L2) ----
#pragma unroll
    for (int nt2 = 0; nt2 < 8; ++nt2) {
#pragma unroll
      for (int ks2 = 0; ks2 < 2; ++ks2) {
        f16x8 vf = *(const f16x8*)&gvt[((uint)((ks2 * 4 + quad) * 128 +
                                               nt2 * 16 + l16)) << 2];
        pv[nt2] = MFMAH(wf[ks2], vf, pv[nt2]);
      }
    }
  }

  // ---- epilogue: C-layout -> global atomicAdd over the 20 j-groups ----
#pragma unroll
  for (int nt2 = 0; nt2 < 8; ++nt2) {
    const int col  = nt2 * 16 + l16;
    const int row0 = ib * BLK + wv * 16 + quad * 4;
#pragma unroll
    for (int rg = 0; rg < 4; ++rg)
      atomicAdd(O + (size_t)(row0 + rg) * DIM + col, pv[nt2][rg]);
  }
}

extern "C" void kernel_launch(void* const* d_in, const int* in_sizes, int n_in,
                              void* d_out, int out_size, void* d_ws, size_t ws_size,
                              hipStream_t stream) {
  (void)in_sizes; (void)n_in; (void)ws_size; (void)out_size;
  const float* q = (const float*)d_in[0];
  const float* k = (const float*)d_in[1];
  const float* v = (const float*)d_in[2];
  float* out = (float*)d_out;
  uint* prep = (uint*)d_ws;   // 64 blocks x 48 KB = 3 MB

  eco_prep_kernel<<<dim3(NB * 4), dim3(NT), 0, stream>>>(k, v, prep, out);
  eco_attn_kernel<<<dim3(NJG, NB), dim3(NT), 0, stream>>>(q, prep, out);
}

// Round 15
// 125.166 us; speedup vs baseline: 1.4605x; 1.2544x over previous
//
#include <hip/hip_runtime.h>
#include <cstdint>
#include <cstddef>

// EcoAttention: block-local top-p truncated attention, S=4096 D=128 BLOCK=64.
//
// R15 = R14's prep-side K-row permutation (in-lane PV weight build; no weight
//       LDS round-trip, no wave-barriers) at R10's PROVEN grid: NJG=16 even
//       (4 j-blocks/WG), __launch_bounds__(256,4), 1024 WGs = exactly 4/CU.
//       R14's NJG=20/5-WG-per-CU widened the per-XCD working set -> L2 spill
//       (FETCH 20->73MB) + atomic line ping-pong (WRITE 53->138MB) + tail.
//       Rule (3x confirmed): scaling is gated by per-XCD L2 capacity.

#define SEQ   4096
#define DIM   128
#define BLK   64
#define NB    (SEQ / BLK)   // 64
#define NJG   16            // j-groups (1024 WGs)
#define JPB   (NB / NJG)    // 4 key blocks per WG
#define NT    256
#define PSTR  12288         // uints per prepped block (Khi 16KB | Kr 16KB | Vt 16KB)
#define THRESH 0.95f
#define EPSF   1e-8f

typedef __attribute__((ext_vector_type(8))) _Float16 f16x8;
typedef __attribute__((ext_vector_type(4))) float    f32x4;

#define MFMAH(a, b, c) __builtin_amdgcn_mfma_f32_16x16x32_f16((a), (b), (c), 0, 0, 0)

union UH4 { uint2 u; _Float16 h[4]; };
union UH8 { uint4 u; f16x8 v; };

__device__ __forceinline__ void gll16(const uint* g, uint* l) {
  __builtin_amdgcn_global_load_lds(
      (const __attribute__((address_space(1))) void*)g,
      (__attribute__((address_space(3))) void*)l, 16, 0, 0);
}

// ---- prep: LDS-free, 4 WGs per key block. Builds [Khi|Kr|Vt-frag] 48KB
//      images (K rows PERMUTED: image row r = nt*16+q*4+rg holds original
//      row o(r) = (nt&1)*32 + q*8 + (nt>>1)*4 + rg) and zeroes O. ----
__global__ __launch_bounds__(NT, 4) void eco_prep_kernel(
    const float* __restrict__ K, const float* __restrict__ V,
    uint* __restrict__ P, float* __restrict__ O) {
  const int tid  = threadIdx.x;
  const int b    = blockIdx.x;     // 0..255
  const int jb   = b >> 2;
  const int part = b & 3;

  // zero O slice (2MB spread over 256 WGs)
  {
    float4 z = {0.f, 0.f, 0.f, 0.f};
    float4* op = (float4*)O;
#pragma unroll
    for (int it = 0; it < 2; ++it) op[b * 512 + it * NT + tid] = z;
  }

  // K 2-term f16 split -> swizzled planes with row permutation
  {
    const float4* gk = (const float4*)(K + (size_t)jb * BLK * DIM);
    uint* dst = P + (size_t)jb * PSTR;
#pragma unroll
    for (int it = 0; it < 2; ++it) {
      int f = part * 512 + it * NT + tid;   // image float4 idx 0..2047
      int r = f >> 5, c4 = f & 31;
      int nt = r >> 4, q = (r >> 2) & 3, rg = r & 3;
      int o  = (nt & 1) * 32 + q * 8 + ((nt >> 1) << 2) + rg;
      float4 x = gk[o * 32 + c4];
      float xs[4] = {x.x, x.y, x.z, x.w};
      UH4 uh, ur;
#pragma unroll
      for (int e = 0; e < 4; ++e) {
        float v = xs[e];
        _Float16 h = (_Float16)v;
        uh.h[e] = h;
        ur.h[e] = (_Float16)(v - (float)h);   // exact residual (Sterbenz)
      }
      uint off = (uint)r * 64u + (((uint)(c4 >> 1) ^ (uint)(r & 15)) << 2) +
                 (uint)((c4 & 1) << 1);
      *(uint2*)&dst[off]        = uh.u;
      *(uint2*)&dst[4096 + off] = ur.u;
    }
  }

  // Vt in PV B-frag linear order (ORIGINAL row order): 1024 fragments;
  // frag idx = ch*128 + d, 8 f16 = V[ch*8+j][d]. One frag/thread.
  {
    const float* gv = V + (size_t)jb * BLK * DIM;
    uint4* dv = (uint4*)(P + (size_t)jb * PSTR + 8192);
    int idx = part * 256 + tid;            // frag idx 0..1023
    int ch = idx >> 7, d = idx & 127;
    UH8 u;
#pragma unroll
    for (int j = 0; j < 8; ++j)
      u.v[j] = (_Float16)gv[(ch * 8 + j) * DIM + d];
    dv[idx] = u.u;
  }
}

// lane-uniform-direction compare-exchange (desc if d)
#define CE(x, y, dmax) { float _hi = fmaxf((x), (y)); float _lo = fminf((x), (y)); \
                         (x) = (dmax) ? _hi : _lo; (y) = (dmax) ? _lo : _hi; }

__global__ __launch_bounds__(NT, 4) void eco_attn_kernel(
    const float* __restrict__ Q, const uint* __restrict__ P,
    float* __restrict__ O) {
  __shared__ __align__(16) uint sK[8192];   // 32 KB: Khi / Kr planes

  const int tid  = threadIdx.x;
  const int ib   = blockIdx.y;
  const int jg   = blockIdx.x;              // 0..15
  const int lane = tid & 63;
  const int wv   = tid >> 6;
  const int quad = lane >> 4;   // 0..3
  const int l16  = lane & 15;
  const int q8   = quad << 3;

  // ---- Q fragments (B-operand): q-row = wv*16+l16, k = ks*32+quad*8+j ----
  f16x8 qh[4], qr[4];
  {
    const float* qp = Q + (size_t)(ib * BLK + wv * 16 + l16) * DIM + quad * 8;
#pragma unroll
    for (int ks = 0; ks < 4; ++ks) {
      float4 x0 = *(const float4*)(qp + ks * 32);
      float4 x1 = *(const float4*)(qp + ks * 32 + 4);
      float xs[8] = {x0.x, x0.y, x0.z, x0.w, x1.x, x1.y, x1.z, x1.w};
      f16x8 h8, r8;
#pragma unroll
      for (int e = 0; e < 8; ++e) {
        float v = xs[e];
        _Float16 h = (_Float16)v;
        h8[e] = h;
        r8[e] = (_Float16)(v - (float)h);
      }
      qh[ks] = h8; qr[ks] = r8;
    }
  }

  const f32x4 zf = {0.f, 0.f, 0.f, 0.f};
  f32x4 pv[8];
#pragma unroll
  for (int i = 0; i < 8; ++i) pv[i] = zf;

  // prologue: stage first K image (32KB = 8 x 16B per thread)
  {
    const uint* gsrc = P + (size_t)(jg * JPB) * PSTR;
#pragma unroll
    for (int it = 0; it < 8; ++it) {
      int idx = (it * NT + tid) << 2;
      gll16(gsrc + idx, sK + idx);
    }
  }

  for (int jj = 0; jj < JPB; ++jj) {
    const int jb = jg * JPB + jj;
    const uint* gvt = P + (size_t)jb * PSTR + 8192;   // Vt frags (L2)
    __syncthreads();  // B1: K image staged (vmcnt drained by barrier)

    // ---- QK^T, operand-swapped: A = K (LDS, permuted rows), B = Q ----
    // Lane (l16,quad) ends with scores at image rows nt*16+quad*4+rg,
    // i.e. original kidx = (nt&1)*32 + quad*8 + (nt>>1)*4 + rg.
    f32x4 ah[4], ar[4];
#pragma unroll
    for (int nt = 0; nt < 4; ++nt) { ah[nt] = zf; ar[nt] = zf; }
#pragma unroll
    for (int nt = 0; nt < 4; ++nt) {
      const int rB = nt * 16 + l16;      // image K-row for the A-frag read
      const uint rowoff = (uint)rB * 64u;
      const uint swk = (uint)(rB & 15);
#pragma unroll
      for (int ks = 0; ks < 4; ++ks) {
        uint off = rowoff + ((((uint)(ks * 4 + quad)) ^ swk) << 2);
        f16x8 bh = *(const f16x8*)&sK[off];
        f16x8 br = *(const f16x8*)&sK[4096 + off];
        ah[nt] = MFMAH(bh, qh[ks], ah[nt]);
        ar[nt] = MFMAH(br, qh[ks], ar[nt]);
        ar[nt] = MFMAH(bh, qr[ks], ar[nt]);
      }
    }
    __syncthreads();  // B0: all waves done reading sK

    // ---- prefetch next K image (overlaps sort + PV below) ----
    if (jj + 1 < JPB) {
      const uint* gsrc = P + (size_t)(jb + 1) * PSTR;
#pragma unroll
      for (int it = 0; it < 8; ++it) {
        int idx = (it * NT + tid) << 2;
        gll16(gsrc + idx, sK + idx);
      }
    }

    // ---- top-p softmax + in-lane weight build; then PV ----
    f16x8 wf[2];
    {
      float a[16], e[16];
#pragma unroll
      for (int nt = 0; nt < 4; ++nt) {
        f32x4 s = ah[nt] + ar[nt];
#pragma unroll
        for (int rg = 0; rg < 4; ++rg) a[nt * 4 + rg] = s[rg];
      }
      // row max: local tree + cross-quad (lanes l16, +16, +32, +48)
      float mt[8];
#pragma unroll
      for (int i = 0; i < 8; ++i) mt[i] = fmaxf(a[i], a[i + 8]);
#pragma unroll
      for (int w2 = 4; w2 >= 1; w2 >>= 1)
#pragma unroll
        for (int i = 0; i < w2; ++i) mt[i] = fmaxf(mt[i], mt[i + w2]);
      float m = mt[0];
      m = fmaxf(m, __shfl_xor(m, 16, 64));
      m = fmaxf(m, __shfl_xor(m, 32, 64));
#pragma unroll
      for (int i = 0; i < 16; ++i) { a[i] = __expf(a[i] - m); e[i] = a[i]; }
      float st[8];
#pragma unroll
      for (int i = 0; i < 8; ++i) st[i] = a[i] + a[i + 8];
#pragma unroll
      for (int w2 = 4; w2 >= 1; w2 >>= 1)
#pragma unroll
        for (int i = 0; i < w2; ++i) st[i] += st[i + w2];
      float sr = st[0];
      sr += __shfl_xor(sr, 16, 64);
      sr += __shfl_xor(sr, 32, 64);
      const float T = THRESH * sr;

      // bitonic sort DESC over 64 = 4 quad-lanes x 16 regs (value-sort;
      // initial permutation irrelevant)
      const int s = quad;
#pragma unroll
      for (int k2 = 2; k2 <= 8; k2 <<= 1)
#pragma unroll
        for (int j2 = k2 >> 1; j2 >= 1; j2 >>= 1)
#pragma unroll
          for (int i = 0; i < 16; ++i) {
            int l = i ^ j2;
            if (l > i) { bool d = ((i & k2) == 0); CE(a[i], a[l], d); }
          }
      const bool x16 = ((s & 1) == 0);
      const bool x32 = ((s & 2) == 0);
#pragma unroll
      for (int j2 = 8; j2 >= 1; j2 >>= 1)
#pragma unroll
        for (int i = 0; i < 16; ++i) {
          int l = i ^ j2;
          if (l > i) { CE(a[i], a[l], x16); }
        }
      {
        const bool km = (x32 == x16);
#pragma unroll
        for (int i = 0; i < 16; ++i) {
          float o = __shfl_xor(a[i], 16, 64);
          a[i] = km ? fmaxf(a[i], o) : fminf(a[i], o);
        }
#pragma unroll
        for (int j2 = 8; j2 >= 1; j2 >>= 1)
#pragma unroll
          for (int i = 0; i < 16; ++i) {
            int l = i ^ j2;
            if (l > i) { CE(a[i], a[l], x32); }
          }
      }
      {
#pragma unroll
        for (int i = 0; i < 16; ++i) {
          float o = __shfl_xor(a[i], 32, 64);
          a[i] = x32 ? fmaxf(a[i], o) : fminf(a[i], o);
        }
#pragma unroll
        for (int i = 0; i < 16; ++i) {
          float o = __shfl_xor(a[i], 16, 64);
          a[i] = x16 ? fmaxf(a[i], o) : fminf(a[i], o);
        }
#pragma unroll
        for (int j2 = 8; j2 >= 1; j2 >>= 1)
#pragma unroll
          for (int i = 0; i < 16; ++i) {
            int l = i ^ j2;
            if (l > i) { CE(a[i], a[l], true); }
          }
      }
      // global inclusive cumsum, count t
#pragma unroll
      for (int i = 1; i < 16; ++i) a[i] += a[i - 1];
      float tot = a[15];
      float c = tot;
      float o1 = __shfl_up(c, 16, 64); if (s >= 1) c += o1;
      float o2 = __shfl_up(c, 32, 64); if (s >= 2) c += o2;
      const float excl = c - tot;
      int cnt = 0;
#pragma unroll
      for (int i = 0; i < 16; ++i) cnt += ((a[i] + excl) < T) ? 1 : 0;
      cnt += __shfl_xor(cnt, 16, 64);
      cnt += __shfl_xor(cnt, 32, 64);
      const int t = cnt;
      // renormalize first-t in ORIGINAL K order:
      // kidx(i) = (nt&1)*32 + quad*8 + (nt>>1)*4 + rg,  i = nt*4+rg
      float p = 0.f;
#pragma unroll
      for (int i = 0; i < 16; ++i) {
        int nt = i >> 2, rg = i & 3;
        int kidx = ((nt & 1) << 5) + q8 + ((nt >> 1) << 2) + rg;
        p += (kidx < t) ? e[i] : 0.f;
      }
      p += __shfl_xor(p, 16, 64);
      p += __shfl_xor(p, 32, 64);
      const float rn = 1.0f / (p + EPSF);
      // in-lane PV A-frag build: wf[ks2][jhi*4+rg] = w(kidx=ks2*32+q8+jhi*4+rg)
      // source element i = (2*jhi+ks2)*4 + rg
#pragma unroll
      for (int ks2 = 0; ks2 < 2; ++ks2) {
        UH8 u;
#pragma unroll
        for (int jhi = 0; jhi < 2; ++jhi)
#pragma unroll
          for (int rg = 0; rg < 4; ++rg) {
            int kidx = (ks2 << 5) + q8 + (jhi << 2) + rg;
            float w = (kidx < t) ? e[(2 * jhi + ks2) * 4 + rg] * rn : 0.f;
            u.v[jhi * 4 + rg] = (_Float16)w;
          }
        wf[ks2] = u.v;
      }
    }

    // ---- PV: A = in-register f16 weights, B = Vt-frag from global (L2) ----
#pragma unroll
    for (int nt2 = 0; nt2 < 8; ++nt2) {
#pragma unroll
      for (int ks2 = 0; ks2 < 2; ++ks2) {
        f16x8 vf = *(const f16x8*)&gvt[((uint)((ks2 * 4 + quad) * 128 +
                                               nt2 * 16 + l16)) << 2];
        pv[nt2] = MFMAH(wf[ks2], vf, pv[nt2]);
      }
    }
  }

  // ---- epilogue: C-layout -> global atomicAdd over the 16 j-groups ----
#pragma unroll
  for (int nt2 = 0; nt2 < 8; ++nt2) {
    const int col  = nt2 * 16 + l16;
    const int row0 = ib * BLK + wv * 16 + quad * 4;
#pragma unroll
    for (int rg = 0; rg < 4; ++rg)
      atomicAdd(O + (size_t)(row0 + rg) * DIM + col, pv[nt2][rg]);
  }
}

extern "C" void kernel_launch(void* const* d_in, const int* in_sizes, int n_in,
                              void* d_out, int out_size, void* d_ws, size_t ws_size,
                              hipStream_t stream) {
  (void)in_sizes; (void)n_in; (void)ws_size; (void)out_size;
  const float* q = (const float*)d_in[0];
  const float* k = (const float*)d_in[1];
  const float* v = (const float*)d_in[2];
  float* out = (float*)d_out;
  uint* prep = (uint*)d_ws;   // 64 blocks x 48 KB = 3 MB

  eco_prep_kernel<<<dim3(NB * 4), dim3(NT), 0, stream>>>(k, v, prep, out);
  eco_attn_kernel<<<dim3(NJG, NB), dim3(NT), 0, stream>>>(q, prep, out);
}